// Round 5
// baseline (1966.061 us; speedup 1.0000x reference)
//
#include <hip/hip_runtime.h>

// RandomMFGL: out[o][g] = (1/4) * sum_n [ (A[n] @ x) @ W[n] + b[n] ]
// A: [4][4096][16384] fp32 = 1.07 GB streamed once -> HBM-bound, floor ~175us.
//
// v4 = measurement round. Facts so far: v1 (scalar-x, scattered A) = 1415us,
// v2 (LDS-x, scattered A) = 1420us, v3b (LDS-coalesced A tiles) = 1554us.
// Coalescing did NOT help -> bottleneck is not request fragmentation. Common
// factor: every wave-instr reads the SAME i-offset across 64KB-strided rows;
// 64KB aliases any power-of-2 L2-slice/channel interleave -> all requests of
// an instr land on ONE slice. The harness fill (contiguous sweep) proves
// 6.3 TB/s is reachable. Also: our kernels never beat the ~680us fills in the
// top-5 table -> k_main < 670us -> dur_us includes the ~680us poison fill.
//
// This round: keep v1 EXACTLY (correctness + baseline) and PREPEND k_rot,
// which recomputes the same partials with a per-lane diagonal K-rotation
// (lane l sweeps its eight 256B sub-chunks in order (m+l)&7 -> each instr's
// 64 requests spread over 8 granules instead of 1). k_rot writes to scratch;
// v1's k_main overwrites hp afterwards -> output provably unchanged.
// dur_us - 1415 = T(k_rot): ~200-260us => aliasing theory right (next round
// drops the v1 pass); ~500-700us => theory wrong, and k_rot enters the top-5
// giving direct FETCH_SIZE/VALUBusy evidence for the A-sweep.

#define N_ENS 4
#define N_OUT 4096
#define N_IN  16384
#define ROWS  (N_ENS * N_OUT)      // 16384 rows (row = n*4096 + o)
#define GSPLIT 32                  // split-K factor
#define ICHUNK (N_IN / GSPLIT)     // 512 i per (row, split)
#define XS_STRIDE 1032             // 64*16 + 8 pad floats per sub-chunk

// ---------------- probe kernel: same partials, diagonal-rotated A sweep ----------------
__global__ __launch_bounds__(256) void k_rot(const float* __restrict__ A,
                                             const float* __restrict__ x,
                                             float* __restrict__ hp2) {
    const int split  = blockIdx.x & (GSPLIT - 1);   // 0..31
    const int rowblk = blockIdx.x >> 5;             // 0..63
    const int tid    = threadIdx.x;
    const int row    = rowblk * 256 + tid;
    const int i0     = split * ICHUNK;

    __shared__ float xs[8 * XS_STRIDE];             // 33 KB, sub-chunk padded

    // stage x-chunk (512 i x 16 f) into padded layout: c = i>>6, j = i&63
    {
        const float4* xg = (const float4*)(x + (size_t)i0 * 16);
#pragma unroll
        for (int q = 0; q < 8; ++q) {
            int fi4 = tid + 256 * q;        // float4 index 0..2047
            float4 v = xg[fi4];
            int F = fi4 * 4;                // float index in chunk
            int i = F >> 4, f = F & 15;
            *(float4*)&xs[(i >> 6) * XS_STRIDE + (i & 63) * 16 + f] = v;
        }
    }
    __syncthreads();

    const float* Ap = A + (size_t)row * N_IN + i0;

    float acc[16];
#pragma unroll
    for (int f = 0; f < 16; ++f) acc[f] = 0.0f;

    for (int m = 0; m < 8; ++m) {                   // 8 sub-chunks of 64 i
        const int c = (m + tid) & 7;                // per-lane rotation
        const float* Asub = Ap + c * 64;
        const float* xsub = &xs[c * XS_STRIDE];
#pragma unroll
        for (int t = 0; t < 4; ++t) {               // 4 x 64 B of A
            float4 av4[4];
#pragma unroll
            for (int q = 0; q < 4; ++q)
                av4[q] = *(const float4*)(Asub + t * 16 + q * 4);
            const float* af = (const float*)av4;
#pragma unroll
            for (int ii = 0; ii < 16; ++ii) {
                const float av = af[ii];
                const float* xp = xsub + (t * 16 + ii) * 16;  // 8-lane-shared -> LDS broadcast
#pragma unroll
                for (int f = 0; f < 16; ++f)
                    acc[f] = fmaf(av, xp[f], acc[f]);
            }
        }
    }

    float* outp = hp2 + ((size_t)split * ROWS + row) * 16;
#pragma unroll
    for (int f = 0; f < 16; ++f) outp[f] = acc[f];
}

// ---------------- kernel 1 (v1 verbatim): hp[split][row][f] ----------------
__global__ __launch_bounds__(256, 6) void k_main(const float* __restrict__ A,
                                                 const float* __restrict__ x,
                                                 float* __restrict__ hp) {
    const int split  = blockIdx.x & (GSPLIT - 1);   // 0..31
    const int rowblk = blockIdx.x >> 5;             // 0..63
    const int row = rowblk * 256 + threadIdx.x;     // lane owns this row
    const int i0 = split * ICHUNK;

    const float* Ap  = A + (size_t)row * N_IN + i0;
    const float* xp0 = x + (size_t)i0 * 16;         // wave-uniform base

    float acc[16];
#pragma unroll
    for (int f = 0; f < 16; ++f) acc[f] = 0.0f;

    for (int s = 0; s < ICHUNK / 16; ++s) {         // 32 iterations, 64 B of A each
        float4 av4[4];
#pragma unroll
        for (int q = 0; q < 4; ++q)
            av4[q] = *(const float4*)(Ap + s * 16 + q * 4);
        const float* af = (const float*)av4;        // lane's 16 consecutive A values
        const float* xp = xp0 + (size_t)s * 256;    // uniform: 16 rows of x, 16 f each

#pragma unroll
        for (int ii = 0; ii < 16; ++ii) {
            const float av = af[ii];
#pragma unroll
            for (int f = 0; f < 16; ++f)
                acc[f] = fmaf(av, xp[ii * 16 + f], acc[f]);   // xp[..] is SGPR-uniform
        }
    }

    float* outp = hp + ((size_t)split * ROWS + row) * 16;   // 64 B per lane, contiguous
#pragma unroll
    for (int f = 0; f < 16; ++f) outp[f] = acc[f];
}

// ---------------- kernel 2: h[row][f] = sum_split hp[split][row][f] ----------------
__global__ __launch_bounds__(256) void k_hsum(const float4* __restrict__ hp,
                                              float4* __restrict__ h) {
    int t = blockIdx.x * 256 + threadIdx.x;   // 0 .. 65535 float4s
    float4 s; s.x = 0.f; s.y = 0.f; s.z = 0.f; s.w = 0.f;
#pragma unroll
    for (int sp = 0; sp < GSPLIT; ++sp) {
        float4 v = hp[(size_t)sp * (ROWS * 4) + t];
        s.x += v.x; s.y += v.y; s.z += v.z; s.w += v.w;
    }
    h[t] = s;
}

// ---------------- kernel 3: out[o][g] = 0.25 * sum_n (sum_f h[n][o][f]*W[n][f][g] + b[n][g]) ----------------
__global__ __launch_bounds__(256) void k_out(const float* __restrict__ h,
                                             const float* __restrict__ Ws,
                                             const float* __restrict__ bs,
                                             float* __restrict__ out) {
    __shared__ float Wsm[N_ENS * 16 * 16];
    __shared__ float bsm[N_ENS * 16];
    int tid = threadIdx.x;
#pragma unroll
    for (int r = 0; r < 4; ++r) Wsm[tid + 256 * r] = Ws[tid + 256 * r];
    if (tid < 64) bsm[tid] = bs[tid];
    __syncthreads();

    int idx = blockIdx.x * 256 + tid;   // 0..65535
    int o = idx >> 4;
    int gg = idx & 15;
    float s = 0.0f;
#pragma unroll
    for (int n = 0; n < N_ENS; ++n) {
        const float* hr = h + ((size_t)(n * N_OUT + o) << 4);
        float t = 0.0f;
#pragma unroll
        for (int f = 0; f < 16; ++f)
            t = fmaf(hr[f], Wsm[n * 256 + f * 16 + gg], t);
        s += t + bsm[n * 16 + gg];
    }
    out[idx] = 0.25f * s;
}

extern "C" void kernel_launch(void* const* d_in, const int* in_sizes, int n_in,
                              void* d_out, int out_size, void* d_ws, size_t ws_size,
                              hipStream_t stream) {
    const float* x  = (const float*)d_in[0];   // [1, 16384, 16]
    const float* As = (const float*)d_in[1];   // [4, 4096, 16384]
    const float* Ws = (const float*)d_in[2];   // [4, 16, 16]
    const float* bs = (const float*)d_in[3];   // [4, 16]
    float* out = (float*)d_out;                // [1, 4096, 16]

    float* hp  = (float*)d_ws;                                     // 32 MB: [32][16384][16]
    float* h   = (float*)((char*)d_ws + (size_t)32 * 1024 * 1024); // 1 MB: [16384][16]
    float* hp2 = (float*)((char*)d_ws + (size_t)64 * 1024 * 1024); // 32 MB probe scratch

    // Probe first (results discarded; hp rewritten by k_main below).
    k_rot<<<64 * GSPLIT, 256, 0, stream>>>(As, x, hp2);

    // hp/h are fully overwritten every call -> no memset needed despite 0xAA poison.
    k_main<<<64 * GSPLIT, 256, 0, stream>>>(As, x, hp);
    k_hsum<<<(ROWS * 16 / 4) / 256, 256, 0, stream>>>((const float4*)hp, (float4*)h);
    k_out<<<(N_OUT * 16) / 256, 256, 0, stream>>>(h, Ws, bs, out);
}